// Round 1
// baseline (27914.639 us; speedup 1.0000x reference)
//
#include <hip/hip_runtime.h>

// ---------------- constants ----------------
constexpr int T_STEPS = 512;
constexpr int IN_DIM  = 1024;
constexpr int H       = 2048;
constexpr int H2      = 4096;
constexpr int OUT_DIM = 1024;

constexpr int NWG  = 256;   // cooperative grid: 1 wg per CU
constexpr int NTHR = 512;   // 8 waves per wg

// workspace layout (in floats)
constexpr size_t OFF_XI   = 0;                       // [512][2048]
constexpr size_t OFF_P    = OFF_XI + (size_t)T_STEPS * H;        // [512][4096]
constexpr size_t OFF_HBUF = OFF_P  + (size_t)T_STEPS * H2;       // [513][2048]
constexpr size_t OFF_A    = OFF_HBUF + (size_t)(T_STEPS + 1) * H; // [4096]
constexpr size_t OFF_Y    = OFF_A + H2;                           // [4096]
constexpr size_t OFF_BAR  = OFF_Y + H2;                           // int region

// ---------------- grid barrier ----------------
__device__ __forceinline__ void grid_barrier(int* cnt, int* gen) {
    __syncthreads();                       // all block stores drained (vmcnt 0)
    if (threadIdx.x == 0) {
        __threadfence();                   // release: flush this XCD's dirty L2 lines
        int g = *(volatile int*)gen;
        int prev = atomicAdd(cnt, 1);      // device-scope by default
        if (prev == NWG - 1) {
            *(volatile int*)cnt = 0;
            __threadfence();
            *(volatile int*)gen = g + 1;   // release next generation
        } else {
            while (*(volatile int*)gen == g) __builtin_amdgcn_s_sleep(2);
        }
        __threadfence();                   // acquire: invalidate L1/L2 before reads
    }
    __syncthreads();
}

__device__ __forceinline__ float wave_reduce(float s) {
    #pragma unroll
    for (int o = 32; o; o >>= 1) s += __shfl_down(s, o, 64);
    return s;
}

// ---------------- sequential recurrence (persistent cooperative kernel) ----------------
__global__ void __launch_bounds__(NTHR, 1) rnn_seq(
    const float* __restrict__ l1w,   // [4096][4096]
    const float* __restrict__ l2w,   // [4096][4096]
    const float* __restrict__ l2b,   // [4096]
    const float* __restrict__ xhw,   // [2048][4096]
    const float* __restrict__ xhb,   // [2048]
    const float* __restrict__ XI,    // [512][2048]
    const float* __restrict__ P,     // [512][4096]  = l1x@xi + l1_b
    float* __restrict__ hbuf,        // [513][2048]
    float* __restrict__ abuf,        // [4096]
    float* __restrict__ ybuf,        // [4096]
    int* __restrict__ bar)
{
    const int wg   = blockIdx.x;
    const int tid  = threadIdx.x;
    const int wave = tid >> 6;
    const int lane = tid & 63;
    int* cnt = bar;
    int* gen = bar + 64;   // separate cacheline from cnt

    for (int t = 0; t < T_STEPS; ++t) {
        const float* __restrict__ h  = hbuf + (size_t)t * H;
        const float* __restrict__ xi = XI   + (size_t)t * H;
        const float* __restrict__ p  = P    + (size_t)t * H2;

        // ---- Stage A: a = relu(P_t + l1_w[:,2048:] @ h) ; 16 rows/wg, wave-per-row
        #pragma unroll
        for (int rr = 0; rr < 2; ++rr) {
            const int r = (wg << 4) + (rr << 3) + wave;
            const float* wrow = l1w + (size_t)r * H2 + H;
            float s = 0.f;
            #pragma unroll
            for (int i = 0; i < H / 256; ++i) {          // 8 iters
                const int idx = (i * 64 + lane) * 4;
                float4 w4 = *(const float4*)(wrow + idx);
                float4 h4 = *(const float4*)(h + idx);
                s += w4.x*h4.x + w4.y*h4.y + w4.z*h4.z + w4.w*h4.w;
            }
            s = wave_reduce(s);
            if (lane == 0) abuf[r] = fmaxf(p[r] + s, 0.f);
        }
        grid_barrier(cnt, gen);

        // ---- Stage B: y = l2_w @ a + l2_b ; 16 rows/wg
        #pragma unroll
        for (int rr = 0; rr < 2; ++rr) {
            const int r = (wg << 4) + (rr << 3) + wave;
            const float* wrow = l2w + (size_t)r * H2;
            float s = 0.f;
            #pragma unroll
            for (int i = 0; i < H2 / 256; ++i) {         // 16 iters
                const int idx = (i * 64 + lane) * 4;
                float4 w4 = *(const float4*)(wrow + idx);
                float4 a4 = *(const float4*)(abuf + idx);
                s += w4.x*a4.x + w4.y*a4.y + w4.z*a4.z + w4.w*a4.w;
            }
            s = wave_reduce(s);
            if (lane == 0) ybuf[r] = l2b[r] + s;
        }
        grid_barrier(cnt, gen);

        // ---- Stage C: h' = xh2h_w @ relu(xh + y) + xh2h_b ; 8 rows/wg
        {
            const int r = (wg << 3) + wave;
            const float* wrow = xhw + (size_t)r * H2;
            float s = 0.f;
            #pragma unroll
            for (int i = 0; i < H / 256; ++i) {          // lower half: xi
                const int idx = (i * 64 + lane) * 4;
                float4 w4 = *(const float4*)(wrow + idx);
                float4 y4 = *(const float4*)(ybuf + idx);
                float4 x4 = *(const float4*)(xi + idx);
                s += w4.x*fmaxf(x4.x + y4.x, 0.f) + w4.y*fmaxf(x4.y + y4.y, 0.f)
                   + w4.z*fmaxf(x4.z + y4.z, 0.f) + w4.w*fmaxf(x4.w + y4.w, 0.f);
            }
            #pragma unroll
            for (int i = 0; i < H / 256; ++i) {          // upper half: h
                const int idx = (i * 64 + lane) * 4;
                float4 w4 = *(const float4*)(wrow + H + idx);
                float4 y4 = *(const float4*)(ybuf + H + idx);
                float4 h4 = *(const float4*)(h + idx);
                s += w4.x*fmaxf(h4.x + y4.x, 0.f) + w4.y*fmaxf(h4.y + y4.y, 0.f)
                   + w4.z*fmaxf(h4.z + y4.z, 0.f) + w4.w*fmaxf(h4.w + y4.w, 0.f);
            }
            s = wave_reduce(s);
            if (lane == 0) hbuf[(size_t)(t + 1) * H + r] = xhb[r] + s;
        }
        grid_barrier(cnt, gen);
    }
}

// ---------------- batched GEMM: C[M,N] = A[M,K] @ B[N,K]^T + bias ----------------
// 128x64 C-tile per wg, 256 threads, each thread 8x4, K-step 32
__global__ void __launch_bounds__(256) gemm_nt(
    const float* __restrict__ A, int lda,
    const float* __restrict__ B, int ldb,
    const float* __restrict__ bias,
    float* __restrict__ C, int ldc, int K)
{
    __shared__ float As[32][129];
    __shared__ float Bs[32][65];
    const int tid = threadIdx.x;
    const int m0 = blockIdx.y * 128, n0 = blockIdx.x * 64;
    const int tx = tid & 15, ty = tid >> 4;

    float acc[8][4] = {};
    for (int k0 = 0; k0 < K; k0 += 32) {
        #pragma unroll
        for (int i = 0; i < 4; ++i) {                 // A: 128x32 = 1024 float4
            const int idx = tid + i * 256;
            const int r = idx >> 3, c4 = idx & 7;
            float4 v = *(const float4*)(A + (size_t)(m0 + r) * lda + k0 + c4 * 4);
            As[c4*4+0][r] = v.x; As[c4*4+1][r] = v.y; As[c4*4+2][r] = v.z; As[c4*4+3][r] = v.w;
        }
        #pragma unroll
        for (int i = 0; i < 2; ++i) {                 // B: 64x32 = 512 float4
            const int idx = tid + i * 256;
            const int r = idx >> 3, c4 = idx & 7;
            float4 v = *(const float4*)(B + (size_t)(n0 + r) * ldb + k0 + c4 * 4);
            Bs[c4*4+0][r] = v.x; Bs[c4*4+1][r] = v.y; Bs[c4*4+2][r] = v.z; Bs[c4*4+3][r] = v.w;
        }
        __syncthreads();
        #pragma unroll
        for (int k = 0; k < 32; ++k) {
            float a[8], b[4];
            #pragma unroll
            for (int i = 0; i < 8; ++i) a[i] = As[k][ty * 8 + i];
            #pragma unroll
            for (int j = 0; j < 4; ++j) b[j] = Bs[k][tx * 4 + j];
            #pragma unroll
            for (int i = 0; i < 8; ++i)
                #pragma unroll
                for (int j = 0; j < 4; ++j)
                    acc[i][j] += a[i] * b[j];
        }
        __syncthreads();
    }
    const float4 bv = *(const float4*)(bias + n0 + tx * 4);
    #pragma unroll
    for (int i = 0; i < 8; ++i) {
        const int m = m0 + ty * 8 + i;
        float4 o;
        o.x = acc[i][0] + bv.x; o.y = acc[i][1] + bv.y;
        o.z = acc[i][2] + bv.z; o.w = acc[i][3] + bv.w;
        *(float4*)(C + (size_t)m * ldc + n0 + tx * 4) = o;
    }
}

// ---------------- launch ----------------
extern "C" void kernel_launch(void* const* d_in, const int* in_sizes, int n_in,
                              void* d_out, int out_size, void* d_ws, size_t ws_size,
                              hipStream_t stream) {
    const float* x      = (const float*)d_in[0];
    const float* h0     = (const float*)d_in[1];
    const float* inp_w  = (const float*)d_in[2];
    const float* inp_b  = (const float*)d_in[3];
    const float* l1_w   = (const float*)d_in[4];
    const float* l1_b   = (const float*)d_in[5];
    const float* l2_w   = (const float*)d_in[6];
    const float* l2_b   = (const float*)d_in[7];
    const float* xh2h_w = (const float*)d_in[8];
    const float* xh2h_b = (const float*)d_in[9];
    const float* out_w  = (const float*)d_in[10];
    const float* out_b  = (const float*)d_in[11];
    float* out = (float*)d_out;

    float* ws   = (float*)d_ws;
    float* XI   = ws + OFF_XI;
    float* P    = ws + OFF_P;
    float* hbuf = ws + OFF_HBUF;
    float* abuf = ws + OFF_A;
    float* ybuf = ws + OFF_Y;
    int*   bar  = (int*)(ws + OFF_BAR);

    // init barrier state (d_ws is poisoned 0xAA before every timed launch)
    hipMemsetAsync(bar, 0, 512, stream);
    // h_0
    hipMemcpyAsync(hbuf, h0, H * sizeof(float), hipMemcpyDeviceToDevice, stream);

    // XI = x @ inp_w^T + inp_b        [512,2048]
    gemm_nt<<<dim3(H / 64, T_STEPS / 128), 256, 0, stream>>>(
        x, IN_DIM, inp_w, IN_DIM, inp_b, XI, H, IN_DIM);
    // P = XI @ l1_w[:, :2048]^T + l1_b   [512,4096]
    gemm_nt<<<dim3(H2 / 64, T_STEPS / 128), 256, 0, stream>>>(
        XI, H, l1_w, H2, l1_b, P, H2, H);

    // sequential recurrence
    {
        void* args[] = {
            (void*)&l1_w, (void*)&l2_w, (void*)&l2_b,
            (void*)&xh2h_w, (void*)&xh2h_b,
            (void*)&XI, (void*)&P, (void*)&hbuf, (void*)&abuf, (void*)&ybuf,
            (void*)&bar
        };
        hipLaunchCooperativeKernel((const void*)rnn_seq, dim3(NWG), dim3(NTHR),
                                   args, 0, stream);
    }

    // ys = H' @ out_w^T + out_b       [512,1024]
    gemm_nt<<<dim3(OUT_DIM / 64, T_STEPS / 128), 256, 0, stream>>>(
        hbuf + H, H, out_w, H, out_b, out, OUT_DIM, H);
    // h_final
    hipMemcpyAsync(out + (size_t)T_STEPS * OUT_DIM, hbuf + (size_t)T_STEPS * H,
                   H * sizeof(float), hipMemcpyDeviceToDevice, stream);
}

// Round 2
// 26751.511 us; speedup vs baseline: 1.0435x; 1.0435x over previous
//
#include <hip/hip_runtime.h>

// ---------------- constants ----------------
constexpr int T_STEPS = 512;
constexpr int IN_DIM  = 1024;
constexpr int H       = 2048;
constexpr int H2      = 4096;
constexpr int OUT_DIM = 1024;

constexpr int NWG  = 256;    // cooperative grid: 1 wg per CU
constexpr int NTHR = 1024;   // 16 waves per wg

// workspace layout (in floats)
constexpr size_t OFF_XI   = 0;                                    // [512][2048]
constexpr size_t OFF_P    = OFF_XI + (size_t)T_STEPS * H;         // [512][4096]
constexpr size_t OFF_HBUF = OFF_P  + (size_t)T_STEPS * H2;        // [513][2048]
constexpr size_t OFF_A    = OFF_HBUF + (size_t)(T_STEPS + 1) * H; // [4096]
constexpr size_t OFF_Y    = OFF_A + H2;                           // [4096]
constexpr size_t OFF_BAR  = OFF_Y + H2;                           // int region

// ---------------- grid barrier ----------------
__device__ __forceinline__ void grid_barrier(int* cnt, int* gen) {
    __syncthreads();                       // all block stores drained
    if (threadIdx.x == 0) {
        __threadfence();                   // release
        int g = *(volatile int*)gen;
        int prev = atomicAdd(cnt, 1);
        if (prev == NWG - 1) {
            *(volatile int*)cnt = 0;
            __threadfence();
            *(volatile int*)gen = g + 1;
        } else {
            while (*(volatile int*)gen == g) __builtin_amdgcn_s_sleep(1);
        }
        __threadfence();                   // acquire
    }
    __syncthreads();
}

__device__ __forceinline__ float wave_reduce(float s) {
    #pragma unroll
    for (int o = 32; o; o >>= 1) s += __shfl_down(s, o, 64);
    return s;
}

__device__ __forceinline__ float dot4(float4 a, float4 b) {
    return a.x*b.x + a.y*b.y + a.z*b.z + a.w*b.w;
}

// ---------------- sequential recurrence (persistent cooperative kernel) ----------------
// LDS: wsA [16][2048] floats (131072 B)  -- stage-A weight rows, pinned all 512 steps
//      az  [4096]     floats (16384 B)   -- shared a-vector (stage B) / z-vector (stage C)
//      sc  [16]       floats             -- stage-C cross-wave partials
__global__ void __launch_bounds__(NTHR, 4) rnn_seq(
    const float* __restrict__ l1w,   // [4096][4096]
    const float* __restrict__ l2w,   // [4096][4096]
    const float* __restrict__ l2b,   // [4096]
    const float* __restrict__ xhw,   // [2048][4096]
    const float* __restrict__ xhb,   // [2048]
    const float* __restrict__ XI,    // [512][2048]
    const float* __restrict__ P,     // [512][4096]
    float* __restrict__ hbuf,        // [513][2048]
    float* __restrict__ abuf,        // [4096]
    float* __restrict__ ybuf,        // [4096]
    int* __restrict__ bar)
{
    const int wg   = blockIdx.x;
    const int tid  = threadIdx.x;
    const int wave = tid >> 6;
    const int lane = tid & 63;
    int* cnt = bar;
    int* gen = bar + 64;

    __shared__ float smem[36880];
    float* wsA = smem;            // 32768 floats
    float* az  = smem + 32768;    // 4096 floats
    float* sc  = smem + 36864;    // 16 floats

    // ---- one-time: pin stage-A (l1_w[:, 2048:]) rows for this wg into LDS
    #pragma unroll
    for (int i = 0; i < 8; ++i) {
        const int idx = tid + (i << 10);        // float4 id, 0..8191
        const int w   = idx >> 9;               // row 0..15
        const int c4  = idx & 511;              // float4 within row
        float4 v = *(const float4*)(l1w + (size_t)((wg << 4) + w) * H2 + H + (c4 << 2));
        *(float4*)(wsA + (w << 11) + (c4 << 2)) = v;
    }
    __syncthreads();

    const int rA = (wg << 4) + wave;                       // stage A/B row
    const float* __restrict__ wrowB = l2w + (size_t)rA * H2;
    const int wC    = wave & 7;
    const int halfC = wave >> 3;
    const int rC    = (wg << 3) + wC;                      // stage C row (2 waves/row)
    const float* __restrict__ wrowC = xhw + (size_t)rC * H2 + (halfC ? H : 0);

    for (int t = 0; t < T_STEPS; ++t) {
        const float* __restrict__ h  = hbuf + (size_t)t * H;
        const float* __restrict__ xi = XI   + (size_t)t * H;
        const float* __restrict__ p  = P    + (size_t)t * H2;

        // ---- Stage A: a[rA] = relu(P_t[rA] + wsA_row . h)
        float s = 0.f;
        #pragma unroll
        for (int i = 0; i < 8; ++i) {
            const int c4 = ((i << 6) + lane) << 2;
            float4 w4 = *(const float4*)(wsA + (wave << 11) + c4);
            float4 h4 = *(const float4*)(h + c4);
            s += dot4(w4, h4);
        }
        s = wave_reduce(s);
        if (lane == 0) abuf[rA] = fmaxf(p[rA] + s, 0.f);

        // prefetch stage-B first half-row (fills during barrier wait)
        float4 wb[8];
        #pragma unroll
        for (int i = 0; i < 8; ++i)
            wb[i] = *(const float4*)(wrowB + (((i << 6) + lane) << 2));

        grid_barrier(cnt, gen);

        // ---- stage a-vector into LDS (one read per wg, not per wave)
        *(float4*)(az + (tid << 2)) = *(const float4*)(abuf + (tid << 2));
        __syncthreads();

        // ---- Stage B: y[rA] = l2b[rA] + wrowB . a
        s = 0.f;
        #pragma unroll
        for (int i = 0; i < 8; ++i) {
            const int c4 = ((i << 6) + lane) << 2;
            float4 a4 = *(const float4*)(az + c4);
            s += dot4(wb[i], a4);
            wb[i] = *(const float4*)(wrowB + ((((i + 8) << 6) + lane) << 2));  // second half
        }
        #pragma unroll
        for (int i = 0; i < 8; ++i) {
            const int c4 = (((i + 8) << 6) + lane) << 2;
            float4 a4 = *(const float4*)(az + c4);
            s += dot4(wb[i], a4);
        }
        s = wave_reduce(s);
        if (lane == 0) ybuf[rA] = l2b[rA] + s;

        // prefetch stage-C half-row (each wave needs exactly 8 float4/lane)
        float4 wc[8];
        #pragma unroll
        for (int i = 0; i < 8; ++i)
            wc[i] = *(const float4*)(wrowC + (((i << 6) + lane) << 2));

        grid_barrier(cnt, gen);

        // ---- stage z = relu(xh + y) into LDS (reuse az)
        {
            const int c = tid << 2;
            float4 yv = *(const float4*)(ybuf + c);
            float4 xv = (tid < 512) ? *(const float4*)(xi + c)
                                    : *(const float4*)(h + c - H);
            float4 zv;
            zv.x = fmaxf(xv.x + yv.x, 0.f);
            zv.y = fmaxf(xv.y + yv.y, 0.f);
            zv.z = fmaxf(xv.z + yv.z, 0.f);
            zv.w = fmaxf(xv.w + yv.w, 0.f);
            *(float4*)(az + c) = zv;
        }
        __syncthreads();

        // ---- Stage C: h'[rC] = xhb[rC] + wrowC-half . z-half   (2 waves per row)
        s = 0.f;
        #pragma unroll
        for (int i = 0; i < 8; ++i) {
            const int c4 = ((((i << 6) + lane) << 2)) + (halfC ? H : 0);
            float4 z4 = *(const float4*)(az + c4);
            s += dot4(wc[i], z4);
        }
        s = wave_reduce(s);
        if (lane == 0) sc[wave] = s;
        __syncthreads();
        if (wave < 8 && lane == 0) {
            float hv = sc[wC] + sc[wC + 8] + xhb[rC];
            hbuf[(size_t)(t + 1) * H + rC] = hv;
        }

        grid_barrier(cnt, gen);
    }
}

// ---------------- batched GEMM: C[M,N] = A[M,K] @ B[N,K]^T + bias ----------------
__global__ void __launch_bounds__(256) gemm_nt(
    const float* __restrict__ A, int lda,
    const float* __restrict__ B, int ldb,
    const float* __restrict__ bias,
    float* __restrict__ C, int ldc, int K)
{
    __shared__ float As[32][129];
    __shared__ float Bs[32][65];
    const int tid = threadIdx.x;
    const int m0 = blockIdx.y * 128, n0 = blockIdx.x * 64;
    const int tx = tid & 15, ty = tid >> 4;

    float acc[8][4] = {};
    for (int k0 = 0; k0 < K; k0 += 32) {
        #pragma unroll
        for (int i = 0; i < 4; ++i) {
            const int idx = tid + i * 256;
            const int r = idx >> 3, c4 = idx & 7;
            float4 v = *(const float4*)(A + (size_t)(m0 + r) * lda + k0 + c4 * 4);
            As[c4*4+0][r] = v.x; As[c4*4+1][r] = v.y; As[c4*4+2][r] = v.z; As[c4*4+3][r] = v.w;
        }
        #pragma unroll
        for (int i = 0; i < 2; ++i) {
            const int idx = tid + i * 256;
            const int r = idx >> 3, c4 = idx & 7;
            float4 v = *(const float4*)(B + (size_t)(n0 + r) * ldb + k0 + c4 * 4);
            Bs[c4*4+0][r] = v.x; Bs[c4*4+1][r] = v.y; Bs[c4*4+2][r] = v.z; Bs[c4*4+3][r] = v.w;
        }
        __syncthreads();
        #pragma unroll
        for (int k = 0; k < 32; ++k) {
            float a[8], b[4];
            #pragma unroll
            for (int i = 0; i < 8; ++i) a[i] = As[k][ty * 8 + i];
            #pragma unroll
            for (int j = 0; j < 4; ++j) b[j] = Bs[k][tx * 4 + j];
            #pragma unroll
            for (int i = 0; i < 8; ++i)
                #pragma unroll
                for (int j = 0; j < 4; ++j)
                    acc[i][j] += a[i] * b[j];
        }
        __syncthreads();
    }
    const float4 bv = *(const float4*)(bias + n0 + tx * 4);
    #pragma unroll
    for (int i = 0; i < 8; ++i) {
        const int m = m0 + ty * 8 + i;
        float4 o;
        o.x = acc[i][0] + bv.x; o.y = acc[i][1] + bv.y;
        o.z = acc[i][2] + bv.z; o.w = acc[i][3] + bv.w;
        *(float4*)(C + (size_t)m * ldc + n0 + tx * 4) = o;
    }
}

// ---------------- launch ----------------
extern "C" void kernel_launch(void* const* d_in, const int* in_sizes, int n_in,
                              void* d_out, int out_size, void* d_ws, size_t ws_size,
                              hipStream_t stream) {
    const float* x      = (const float*)d_in[0];
    const float* h0     = (const float*)d_in[1];
    const float* inp_w  = (const float*)d_in[2];
    const float* inp_b  = (const float*)d_in[3];
    const float* l1_w   = (const float*)d_in[4];
    const float* l1_b   = (const float*)d_in[5];
    const float* l2_w   = (const float*)d_in[6];
    const float* l2_b   = (const float*)d_in[7];
    const float* xh2h_w = (const float*)d_in[8];
    const float* xh2h_b = (const float*)d_in[9];
    const float* out_w  = (const float*)d_in[10];
    const float* out_b  = (const float*)d_in[11];
    float* out = (float*)d_out;

    float* ws   = (float*)d_ws;
    float* XI   = ws + OFF_XI;
    float* P    = ws + OFF_P;
    float* hbuf = ws + OFF_HBUF;
    float* abuf = ws + OFF_A;
    float* ybuf = ws + OFF_Y;
    int*   bar  = (int*)(ws + OFF_BAR);

    hipMemsetAsync(bar, 0, 512, stream);
    hipMemcpyAsync(hbuf, h0, H * sizeof(float), hipMemcpyDeviceToDevice, stream);

    // XI = x @ inp_w^T + inp_b        [512,2048]
    gemm_nt<<<dim3(H / 64, T_STEPS / 128), 256, 0, stream>>>(
        x, IN_DIM, inp_w, IN_DIM, inp_b, XI, H, IN_DIM);
    // P = XI @ l1_w[:, :2048]^T + l1_b   [512,4096]
    gemm_nt<<<dim3(H2 / 64, T_STEPS / 128), 256, 0, stream>>>(
        XI, H, l1_w, H2, l1_b, P, H2, H);

    {
        void* args[] = {
            (void*)&l1_w, (void*)&l2_w, (void*)&l2_b,
            (void*)&xh2h_w, (void*)&xh2h_b,
            (void*)&XI, (void*)&P, (void*)&hbuf, (void*)&abuf, (void*)&ybuf,
            (void*)&bar
        };
        hipLaunchCooperativeKernel((const void*)rnn_seq, dim3(NWG), dim3(NTHR),
                                   args, 0, stream);
    }

    // ys = H' @ out_w^T + out_b       [512,1024]
    gemm_nt<<<dim3(OUT_DIM / 64, T_STEPS / 128), 256, 0, stream>>>(
        hbuf + H, H, out_b ? out_w : out_w, H, out_b, out, OUT_DIM, H);
    hipMemcpyAsync(out + (size_t)T_STEPS * OUT_DIM, hbuf + (size_t)T_STEPS * H,
                   H * sizeof(float), hipMemcpyDeviceToDevice, stream);
}

// Round 4
// 10964.566 us; speedup vs baseline: 2.5459x; 2.4398x over previous
//
#include <hip/hip_runtime.h>

typedef unsigned long long ull;

// ---------------- constants ----------------
constexpr int T_STEPS = 512;
constexpr int IN_DIM  = 1024;
constexpr int H       = 2048;
constexpr int H2      = 4096;
constexpr int OUT_DIM = 1024;

constexpr int NWG  = 256;    // cooperative grid: 1 wg per CU
constexpr int NTHR = 1024;   // 16 waves per wg

// workspace layout (in floats)
constexpr size_t OFF_XI   = 0;                                    // [512][2048]
constexpr size_t OFF_P    = OFF_XI + (size_t)T_STEPS * H;         // [512][4096]
constexpr size_t OFF_HBUF = OFF_P  + (size_t)T_STEPS * H2;        // [513][2048]
constexpr size_t OFF_A    = OFF_HBUF + (size_t)(T_STEPS + 1) * H; // [4096]
constexpr size_t OFF_Y    = OFF_A + H2;                           // [4096]
constexpr size_t OFF_BAR  = OFF_Y + H2;                           // u64 barrier word

// ---------------- coherent (LLC-level) access helpers: sc0 sc1, NO cache invalidation
__device__ __forceinline__ float load_cohf(const float* p) {
    return __hip_atomic_load(p, __ATOMIC_RELAXED, __HIP_MEMORY_SCOPE_AGENT);
}
__device__ __forceinline__ ull load_coh8(const ull* p) {
    return __hip_atomic_load(p, __ATOMIC_RELAXED, __HIP_MEMORY_SCOPE_AGENT);
}
__device__ __forceinline__ void store_cohf(float* p, float v) {
    __hip_atomic_store(p, v, __ATOMIC_RELAXED, __HIP_MEMORY_SCOPE_AGENT);
}

// ---------------- fence-free grid barrier: (gen<<32 | count) in one u64
__device__ __forceinline__ void grid_barrier(ull* bar) {
    __syncthreads();   // drains vmcnt: all sc0sc1 stores of this block are at the LLC
    if (threadIdx.x == 0) {
        ull old = __hip_atomic_fetch_add(bar, 1ull, __ATOMIC_RELAXED,
                                         __HIP_MEMORY_SCOPE_AGENT);
        unsigned arrived = (unsigned)(old & 0xffffffffu);
        unsigned gen     = (unsigned)(old >> 32);
        if (arrived == NWG - 1) {
            // reset count AND bump gen in one atomic op — no ordering hazard
            __hip_atomic_fetch_add(bar, (1ull << 32) - (ull)NWG, __ATOMIC_RELAXED,
                                   __HIP_MEMORY_SCOPE_AGENT);
        } else {
            while ((unsigned)(__hip_atomic_load(bar, __ATOMIC_RELAXED,
                                                __HIP_MEMORY_SCOPE_AGENT) >> 32) == gen)
                __builtin_amdgcn_s_sleep(1);
        }
    }
    __syncthreads();
}

__device__ __forceinline__ float wave_reduce(float s) {
    #pragma unroll
    for (int o = 32; o; o >>= 1) s += __shfl_down(s, o, 64);
    return s;
}

__device__ __forceinline__ float dot4(float4 a, float4 b) {
    return a.x*b.x + a.y*b.y + a.z*b.z + a.w*b.w;
}

union U8 { ull u; float2 f; };

// ---------------- sequential recurrence (persistent cooperative kernel) ----------------
// LDS: wsA [16][2048] f32 (131072 B)  stage-A weight rows, pinned all 512 steps
//      hz  [2048] f32 (8192 B)        h_t staged once per step
//      az  [4096] f32 (16384 B)       a-vector (stage B) / z-vector (stage C)
//      sc  [16]   f32                 stage-C cross-wave partials
__global__ void __launch_bounds__(NTHR, 4) rnn_seq(
    const float* __restrict__ l1w,   // [4096][4096]
    const float* __restrict__ l2w,   // [4096][4096]
    const float* __restrict__ l2b,   // [4096]
    const float* __restrict__ xhw,   // [2048][4096]
    const float* __restrict__ xhb,   // [2048]
    const float* __restrict__ XI,    // [512][2048]
    const float* __restrict__ P,     // [512][4096]
    float* __restrict__ hbuf,        // [513][2048]
    float* __restrict__ abuf,        // [4096]
    float* __restrict__ ybuf,        // [4096]
    ull* __restrict__ bar)
{
    const int wg   = blockIdx.x;
    const int tid  = threadIdx.x;
    const int wave = tid >> 6;
    const int lane = tid & 63;

    __shared__ float smem[38928];
    float* wsA = smem;            // 32768 floats
    float* hz  = smem + 32768;    // 2048 floats
    float* az  = smem + 34816;    // 4096 floats
    float* sc  = smem + 38912;    // 16 floats

    // ---- one-time: pin stage-A (l1_w[:, 2048:]) rows for this wg into LDS
    #pragma unroll
    for (int i = 0; i < 8; ++i) {
        const int idx = tid + (i << 10);        // float4 id, 0..8191
        const int w   = idx >> 9;               // row 0..15
        const int c4  = idx & 511;              // float4 within row
        float4 v = *(const float4*)(l1w + (size_t)((wg << 4) + w) * H2 + H + (c4 << 2));
        *(float4*)(wsA + (w << 11) + (c4 << 2)) = v;
    }
    __syncthreads();

    const int rA = (wg << 4) + wave;                       // stage A/B row
    const float* __restrict__ wrowB = l2w + (size_t)rA * H2;
    const int wC    = wave & 7;
    const int halfC = wave >> 3;
    const int rC    = (wg << 3) + wC;                      // stage C row (2 waves/row)
    const float* __restrict__ wrowC = xhw + (size_t)rC * H2 + (halfC ? H : 0);

    for (int t = 0; t < T_STEPS; ++t) {
        const float* __restrict__ xi = XI + (size_t)t * H;
        const float* __restrict__ p  = P  + (size_t)t * H2;

        // ---- stage h_t into LDS (coherent 8B loads, one per thread)
        {
            const ull* hsrc = (const ull*)(hbuf + (size_t)t * H);   // 1024 ulls
            U8 u; u.u = load_coh8(hsrc + tid);
            *(float2*)(hz + (tid << 1)) = u.f;
        }
        __syncthreads();

        // ---- Stage A: a[rA] = relu(P_t[rA] + wsA_row . h)   (all-LDS)
        float s = 0.f;
        #pragma unroll
        for (int i = 0; i < 8; ++i) {
            const int c4 = ((i << 6) + lane) << 2;
            float4 w4 = *(const float4*)(wsA + (wave << 11) + c4);
            float4 h4 = *(const float4*)(hz + c4);
            s += dot4(w4, h4);
        }
        s = wave_reduce(s);
        if (lane == 0) store_cohf(abuf + rA, fmaxf(p[rA] + s, 0.f));

        // prefetch full stage-B row (16 float4 in flight; fills during barrier)
        float4 wb[16];
        #pragma unroll
        for (int i = 0; i < 16; ++i)
            wb[i] = *(const float4*)(wrowB + (((i << 6) + lane) << 2));

        grid_barrier(bar);

        // ---- stage a-vector into LDS (coherent 8B loads)
        {
            const ull* a8 = (const ull*)abuf;   // 2048 ulls
            U8 u0; u0.u = load_coh8(a8 + tid);
            U8 u1; u1.u = load_coh8(a8 + tid + 1024);
            *(float2*)(az + (tid << 1))        = u0.f;
            *(float2*)(az + (tid << 1) + 2048) = u1.f;
        }
        __syncthreads();

        // ---- Stage B: y[rA] = l2b[rA] + wrowB . a
        s = 0.f;
        #pragma unroll
        for (int i = 0; i < 16; ++i) {
            const int c4 = ((i << 6) + lane) << 2;
            float4 a4 = *(const float4*)(az + c4);
            s += dot4(wb[i], a4);
        }
        s = wave_reduce(s);
        if (lane == 0) store_cohf(ybuf + rA, l2b[rA] + s);

        // prefetch stage-C half-row (8 float4)
        float4 wc[8];
        #pragma unroll
        for (int i = 0; i < 8; ++i)
            wc[i] = *(const float4*)(wrowC + (((i << 6) + lane) << 2));

        grid_barrier(bar);

        // ---- stage z = relu(xh + y) into LDS (reuse az); y coherent, xh from XI/hz
        {
            const int c = tid << 2;
            U8 y0; y0.u = load_coh8((const ull*)ybuf + (tid << 1));
            U8 y1; y1.u = load_coh8((const ull*)ybuf + (tid << 1) + 1);
            float4 xv = (tid < 512) ? *(const float4*)(xi + c)
                                    : *(const float4*)(hz + c - H);
            float4 zv;
            zv.x = fmaxf(xv.x + y0.f.x, 0.f);
            zv.y = fmaxf(xv.y + y0.f.y, 0.f);
            zv.z = fmaxf(xv.z + y1.f.x, 0.f);
            zv.w = fmaxf(xv.w + y1.f.y, 0.f);
            *(float4*)(az + c) = zv;
        }
        __syncthreads();

        // ---- Stage C: h'[rC] = xhb[rC] + wrowC-half . z-half   (2 waves per row)
        s = 0.f;
        {
            const int base = halfC ? H : 0;
            #pragma unroll
            for (int i = 0; i < 8; ++i) {
                const int c4 = (((i << 6) + lane) << 2) + base;
                float4 z4 = *(const float4*)(az + c4);
                s += dot4(wc[i], z4);
            }
        }
        s = wave_reduce(s);
        if (lane == 0) sc[wave] = s;
        __syncthreads();
        if (wave < 8 && lane == 0)
            store_cohf(hbuf + (size_t)(t + 1) * H + rC, sc[wC] + sc[wC + 8] + xhb[rC]);

        grid_barrier(bar);
    }
}

// ---------------- batched GEMM: C[M,N] = A[M,K] @ B[N,K]^T + bias ----------------
__global__ void __launch_bounds__(256) gemm_nt(
    const float* __restrict__ A, int lda,
    const float* __restrict__ B, int ldb,
    const float* __restrict__ bias,
    float* __restrict__ C, int ldc, int K)
{
    __shared__ float As[32][129];
    __shared__ float Bs[32][65];
    const int tid = threadIdx.x;
    const int m0 = blockIdx.y * 128, n0 = blockIdx.x * 64;
    const int tx = tid & 15, ty = tid >> 4;

    float acc[8][4] = {};
    for (int k0 = 0; k0 < K; k0 += 32) {
        #pragma unroll
        for (int i = 0; i < 4; ++i) {
            const int idx = tid + i * 256;
            const int r = idx >> 3, c4 = idx & 7;
            float4 v = *(const float4*)(A + (size_t)(m0 + r) * lda + k0 + c4 * 4);
            As[c4*4+0][r] = v.x; As[c4*4+1][r] = v.y; As[c4*4+2][r] = v.z; As[c4*4+3][r] = v.w;
        }
        #pragma unroll
        for (int i = 0; i < 2; ++i) {
            const int idx = tid + i * 256;
            const int r = idx >> 3, c4 = idx & 7;
            float4 v = *(const float4*)(B + (size_t)(n0 + r) * ldb + k0 + c4 * 4);
            Bs[c4*4+0][r] = v.x; Bs[c4*4+1][r] = v.y; Bs[c4*4+2][r] = v.z; Bs[c4*4+3][r] = v.w;
        }
        __syncthreads();
        #pragma unroll
        for (int k = 0; k < 32; ++k) {
            float a[8], b[4];
            #pragma unroll
            for (int i = 0; i < 8; ++i) a[i] = As[k][ty * 8 + i];
            #pragma unroll
            for (int j = 0; j < 4; ++j) b[j] = Bs[k][tx * 4 + j];
            #pragma unroll
            for (int i = 0; i < 8; ++i)
                #pragma unroll
                for (int j = 0; j < 4; ++j)
                    acc[i][j] += a[i] * b[j];
        }
        __syncthreads();
    }
    const float4 bv = *(const float4*)(bias + n0 + tx * 4);
    #pragma unroll
    for (int i = 0; i < 8; ++i) {
        const int m = m0 + ty * 8 + i;
        float4 o;
        o.x = acc[i][0] + bv.x; o.y = acc[i][1] + bv.y;
        o.z = acc[i][2] + bv.z; o.w = acc[i][3] + bv.w;
        *(float4*)(C + (size_t)m * ldc + n0 + tx * 4) = o;
    }
}

// ---------------- launch ----------------
extern "C" void kernel_launch(void* const* d_in, const int* in_sizes, int n_in,
                              void* d_out, int out_size, void* d_ws, size_t ws_size,
                              hipStream_t stream) {
    const float* x      = (const float*)d_in[0];
    const float* h0     = (const float*)d_in[1];
    const float* inp_w  = (const float*)d_in[2];
    const float* inp_b  = (const float*)d_in[3];
    const float* l1_w   = (const float*)d_in[4];
    const float* l1_b   = (const float*)d_in[5];
    const float* l2_w   = (const float*)d_in[6];
    const float* l2_b   = (const float*)d_in[7];
    const float* xh2h_w = (const float*)d_in[8];
    const float* xh2h_b = (const float*)d_in[9];
    const float* out_w  = (const float*)d_in[10];
    const float* out_b  = (const float*)d_in[11];
    float* out = (float*)d_out;

    float* ws   = (float*)d_ws;
    float* XI   = ws + OFF_XI;
    float* P    = ws + OFF_P;
    float* hbuf = ws + OFF_HBUF;
    float* abuf = ws + OFF_A;
    float* ybuf = ws + OFF_Y;
    ull*   bar  = (ull*)(ws + OFF_BAR);

    hipMemsetAsync(bar, 0, 64, stream);
    hipMemcpyAsync(hbuf, h0, H * sizeof(float), hipMemcpyDeviceToDevice, stream);

    // XI = x @ inp_w^T + inp_b        [512,2048]
    gemm_nt<<<dim3(H / 64, T_STEPS / 128), 256, 0, stream>>>(
        x, IN_DIM, inp_w, IN_DIM, inp_b, XI, H, IN_DIM);
    // P = XI @ l1_w[:, :2048]^T + l1_b   [512,4096]
    gemm_nt<<<dim3(H2 / 64, T_STEPS / 128), 256, 0, stream>>>(
        XI, H, l1_w, H2, l1_b, P, H2, H);

    {
        void* args[] = {
            (void*)&l1_w, (void*)&l2_w, (void*)&l2_b,
            (void*)&xh2h_w, (void*)&xh2h_b,
            (void*)&XI, (void*)&P, (void*)&hbuf, (void*)&abuf, (void*)&ybuf,
            (void*)&bar
        };
        hipLaunchCooperativeKernel((const void*)rnn_seq, dim3(NWG), dim3(NTHR),
                                   args, 0, stream);
    }

    // ys = H' @ out_w^T + out_b       [512,1024]
    gemm_nt<<<dim3(OUT_DIM / 64, T_STEPS / 128), 256, 0, stream>>>(
        hbuf + H, H, out_w, H, out_b, out, OUT_DIM, H);
    hipMemcpyAsync(out + (size_t)T_STEPS * OUT_DIM, hbuf + (size_t)T_STEPS * H,
                   H * sizeof(float), hipMemcpyDeviceToDevice, stream);
}